// Round 1
// baseline (2300.232 us; speedup 1.0000x reference)
//
#include <hip/hip_runtime.h>

#define B_ 16
#define T_ 128
#define H_ 512
#define V_ 50257
#define VP_ 50304            // 393*128 (padded V)
#define NBLK 393             // VP_/128
#define M_ (B_*T_)           // 2048 rows (t*16+b)
#define N4H 2048             // 4*H
#define KH 512               // K of hidden GEMMs
#define NKB 16               // KH/32

typedef __attribute__((ext_vector_type(8))) short short8;   // bf16x8 frag (guide-verified type)
typedef __attribute__((ext_vector_type(4))) float floatx4;

static __device__ __forceinline__ unsigned short f2bf(float f) {
    unsigned int u = __builtin_bit_cast(unsigned int, f);
    unsigned int r = (u + 0x7FFFu + ((u >> 16) & 1u)) >> 16;
    return (unsigned short)r;
}

// ---------------- init: zero states, precompute per-row label ----------------
__global__ void k_init(const int* __restrict__ labels, int* __restrict__ lab_r,
                       float* __restrict__ c1, float* __restrict__ c2,
                       unsigned short* __restrict__ h0) {
    int tid = blockIdx.x * blockDim.x + threadIdx.x;
    if (tid < M_) {
        int t = tid >> 4, b = tid & 15;
        lab_r[tid] = labels[b * T_ + t];   // row order is t*16+b; labels flat is b*T+t
    }
    if (tid < B_ * H_) {
        c1[tid] = 0.f; c2[tid] = 0.f; h0[tid] = 0;  // bf16 zero == 0x0000
    }
}

// ---------------- embedding gather -> bf16 X [T*B, H] (row = t*16+b) ----------------
__global__ void k_embed(const int* __restrict__ tokens, const float* __restrict__ emb,
                        unsigned short* __restrict__ X) {
    int tid = blockIdx.x * blockDim.x + threadIdx.x;
    if (tid >= M_ * H_) return;
    int row = tid >> 9, col = tid & 511;
    int t = row >> 4, b = row & 15;
    int tok = tokens[b * T_ + t];
    X[tid] = f2bf(emb[(size_t)tok * H_ + col]);
}

// ---------------- pack fp32 weight slab [512 x ld] into MFMA B-frag order (bf16) ----------------
// chunk = nt*NKB + kb; within chunk lane l holds B[kb*32 + (l>>4)*8 + j][nt*16 + (l&15)], j=0..7
__global__ void k_pack(const float* __restrict__ src, int ld, int nvalid, int nchunks,
                       unsigned short* __restrict__ dst) {
    int tid = blockIdx.x * blockDim.x + threadIdx.x;
    int lane = tid & 63, chunk = tid >> 6;
    if (chunk >= nchunks) return;
    int nt = chunk >> 4, kb = chunk & 15;
    int n = nt * 16 + (lane & 15);
    int k = kb * 32 + ((lane >> 4) << 3);
    unsigned short vals[8];
    if (n < nvalid) {
#pragma unroll
        for (int j = 0; j < 8; ++j) vals[j] = f2bf(src[(size_t)(k + j) * ld + n]);
    } else {
#pragma unroll
        for (int j = 0; j < 8; ++j) vals[j] = 0;
    }
    *(short8*)(dst + (size_t)chunk * 512 + lane * 8) = *(short8*)vals;
}

// ---------------- big GEMM + bias: Z[M, 2048] = A[M,512](bf16) @ Bp + bias ----------------
// grid (bn=16, bm=16), 256 thr = 4 waves (2m x 2n), wave tile 64x64
__global__ __launch_bounds__(256, 2) void k_gemm_bias(
        const unsigned short* __restrict__ A, const unsigned short* __restrict__ Bp,
        const float* __restrict__ bias, float* __restrict__ C) {
    int bn = blockIdx.x, bm = blockIdx.y;
    int tid = threadIdx.x, lane = tid & 63, w = tid >> 6;
    int wm = w >> 1, wn = w & 1;
    int l15 = lane & 15, quad = lane >> 4;
    floatx4 acc[4][4];
#pragma unroll
    for (int i = 0; i < 4; ++i)
#pragma unroll
        for (int j = 0; j < 4; ++j) acc[i][j] = (floatx4){0.f, 0.f, 0.f, 0.f};
    const unsigned short* Abase = A + (size_t)(bm * 128 + wm * 64 + l15) * KH + quad * 8;
    int ntg0 = bn * 8 + wn * 4;
#pragma unroll 4
    for (int kb = 0; kb < NKB; ++kb) {
        short8 af[4], bf[4];
#pragma unroll
        for (int mt = 0; mt < 4; ++mt) af[mt] = *(const short8*)(Abase + mt * 16 * KH + kb * 32);
#pragma unroll
        for (int nt = 0; nt < 4; ++nt)
            bf[nt] = *(const short8*)(Bp + ((size_t)(ntg0 + nt) * NKB + kb) * 512 + lane * 8);
#pragma unroll
        for (int mt = 0; mt < 4; ++mt)
#pragma unroll
            for (int nt = 0; nt < 4; ++nt)
                acc[mt][nt] = __builtin_amdgcn_mfma_f32_16x16x32_bf16(af[mt], bf[nt], acc[mt][nt], 0, 0, 0);
    }
#pragma unroll
    for (int nt = 0; nt < 4; ++nt) {
        int col = bn * 128 + wn * 64 + nt * 16 + l15;
        float bv = bias[col];
#pragma unroll
        for (int mt = 0; mt < 4; ++mt) {
            int row0 = bm * 128 + wm * 64 + mt * 16 + quad * 4;
#pragma unroll
            for (int r = 0; r < 4; ++r)
                C[(size_t)(row0 + r) * N4H + col] = acc[mt][nt][r] + bv;
        }
    }
}

// ---------------- one LSTM cell step: z = Zpre_t + hprev@Wh; gate math; update c, h ----------------
// grid 16 blocks; block j covers units [j*32, j*32+32); wave g handles gate g (cols g*512 + ...)
__global__ __launch_bounds__(256) void k_lstm_step(
        const float* __restrict__ Zpre_t, const unsigned short* __restrict__ hprev,
        const unsigned short* __restrict__ WhP, float* __restrict__ c,
        unsigned short* __restrict__ hout) {
    int j = blockIdx.x;
    int tid = threadIdx.x, lane = tid & 63, g = tid >> 6;
    int l15 = lane & 15, quad = lane >> 4;
    __shared__ float zs[4 * 32 * 17];
    floatx4 acc0 = (floatx4){0.f, 0.f, 0.f, 0.f};
    floatx4 acc1 = (floatx4){0.f, 0.f, 0.f, 0.f};
    const unsigned short* Abase = hprev + l15 * H_ + quad * 8;
    int ntg0 = g * 32 + j * 2;   // (g*512 + j*32)/16
#pragma unroll 4
    for (int kb = 0; kb < NKB; ++kb) {
        short8 af = *(const short8*)(Abase + kb * 32);
        short8 b0 = *(const short8*)(WhP + ((size_t)ntg0 * NKB + kb) * 512 + lane * 8);
        short8 b1 = *(const short8*)(WhP + ((size_t)(ntg0 + 1) * NKB + kb) * 512 + lane * 8);
        acc0 = __builtin_amdgcn_mfma_f32_16x16x32_bf16(af, b0, acc0, 0, 0, 0);
        acc1 = __builtin_amdgcn_mfma_f32_16x16x32_bf16(af, b1, acc1, 0, 0, 0);
    }
#pragma unroll
    for (int nt = 0; nt < 2; ++nt) {
        int ucol = nt * 16 + l15;                    // 0..31
        int col = g * 512 + j * 32 + ucol;           // z column
        floatx4 a = nt ? acc1 : acc0;
#pragma unroll
        for (int r = 0; r < 4; ++r) {
            int b = quad * 4 + r;
            zs[(g * 32 + ucol) * 17 + b] = a[r] + Zpre_t[(size_t)b * N4H + col];
        }
    }
    __syncthreads();
    for (int p = tid; p < 32 * 16; p += 256) {
        int u = p >> 4, b = p & 15;
        float zi = zs[(0 * 32 + u) * 17 + b];
        float zj = zs[(1 * 32 + u) * 17 + b];
        float zf = zs[(2 * 32 + u) * 17 + b];
        float zo = zs[(3 * 32 + u) * 17 + b];
        int ug = j * 32 + u;
        float cold = c[b * H_ + ug];
        float si = 1.f / (1.f + expf(-zi));
        float sf = 1.f / (1.f + expf(-zf));
        float so = 1.f / (1.f + expf(-zo));
        float cn = cold * sf + si * tanhf(zj);
        float hn = tanhf(cn) * so;
        c[b * H_ + ug] = cn;
        hout[b * H_ + ug] = f2bf(hn);
    }
}

// ---------------- logits GEMM + fused online-softmax partials ----------------
// grid (bn=393, bm=16); per block 128x128 logits tile; writes per-(row,bn) max & sumexp + label logit
__global__ __launch_bounds__(256, 2) void k_logits(
        const unsigned short* __restrict__ A, const unsigned short* __restrict__ Bp,
        const float* __restrict__ sb, const int* __restrict__ lab_r,
        float* __restrict__ pm, float* __restrict__ ps, float* __restrict__ labv) {
    int bn = blockIdx.x, bm = blockIdx.y;
    int tid = threadIdx.x, lane = tid & 63, w = tid >> 6;
    int wm = w >> 1, wn = w & 1;
    int l15 = lane & 15, quad = lane >> 4;
    floatx4 acc[4][4];
#pragma unroll
    for (int i = 0; i < 4; ++i)
#pragma unroll
        for (int j = 0; j < 4; ++j) acc[i][j] = (floatx4){0.f, 0.f, 0.f, 0.f};
    const unsigned short* Abase = A + (size_t)(bm * 128 + wm * 64 + l15) * KH + quad * 8;
    int ntg0 = bn * 8 + wn * 4;
#pragma unroll 4
    for (int kb = 0; kb < NKB; ++kb) {
        short8 af[4], bf[4];
#pragma unroll
        for (int mt = 0; mt < 4; ++mt) af[mt] = *(const short8*)(Abase + mt * 16 * KH + kb * 32);
#pragma unroll
        for (int nt = 0; nt < 4; ++nt)
            bf[nt] = *(const short8*)(Bp + ((size_t)(ntg0 + nt) * NKB + kb) * 512 + lane * 8);
#pragma unroll
        for (int mt = 0; mt < 4; ++mt)
#pragma unroll
            for (int nt = 0; nt < 4; ++nt)
                acc[mt][nt] = __builtin_amdgcn_mfma_f32_16x16x32_bf16(af[mt], bf[nt], acc[mt][nt], 0, 0, 0);
    }
    // epilogue: add bias, mask cols >= V, per-row max & sumexp over this 128-col tile
    __shared__ float lmax[2][128];
    __shared__ float lsum[2][128];
    float bv[4]; int colg[4]; bool valid[4];
#pragma unroll
    for (int nt = 0; nt < 4; ++nt) {
        colg[nt] = bn * 128 + wn * 64 + nt * 16 + l15;
        valid[nt] = colg[nt] < V_;
        bv[nt] = valid[nt] ? sb[colg[nt]] : 0.f;
    }
#pragma unroll
    for (int mt = 0; mt < 4; ++mt) {
        float rmax[4], rsum[4];
#pragma unroll
        for (int r = 0; r < 4; ++r) {
            float m = -3.0e38f;
#pragma unroll
            for (int nt = 0; nt < 4; ++nt) {
                float v = valid[nt] ? acc[mt][nt][r] + bv[nt] : -3.0e38f;
                acc[mt][nt][r] = v;            // keep biased/masked value
                m = fmaxf(m, v);
            }
#pragma unroll
            for (int d = 1; d < 16; d <<= 1) m = fmaxf(m, __shfl_xor(m, d, 16));
            rmax[r] = m;
            float s = 0.f;
#pragma unroll
            for (int nt = 0; nt < 4; ++nt)
                if (valid[nt]) s += __expf(acc[mt][nt][r] - m);
#pragma unroll
            for (int d = 1; d < 16; d <<= 1) s += __shfl_xor(s, d, 16);
            rsum[r] = s;
        }
#pragma unroll
        for (int r = 0; r < 4; ++r) {
            int lrow = wm * 64 + mt * 16 + quad * 4 + r;
            int rowg = bm * 128 + lrow;
            int lc = lab_r[rowg];
#pragma unroll
            for (int nt = 0; nt < 4; ++nt)
                if (valid[nt] && colg[nt] == lc) labv[rowg] = acc[mt][nt][r];
            if (l15 == 0) { lmax[wn][lrow] = rmax[r]; lsum[wn][lrow] = rsum[r]; }
        }
    }
    __syncthreads();
    if (tid < 128) {
        float m0 = lmax[0][tid], m1 = lmax[1][tid];
        float m = fmaxf(m0, m1);
        float s = 0.f;
        if (m0 > -1.0e30f) s += lsum[0][tid] * __expf(m0 - m);
        if (m1 > -1.0e30f) s += lsum[1][tid] * __expf(m1 - m);
        int rowg = bm * 128 + tid;
        pm[(size_t)rowg * NBLK + bn] = m;
        ps[(size_t)rowg * NBLK + bn] = s;
    }
}

// ---------------- per-row reduction over the 393 tiles ----------------
__global__ void k_rowreduce(const float* __restrict__ pm, const float* __restrict__ ps,
                            const float* __restrict__ labv, float* __restrict__ ll) {
    int row = blockIdx.x;
    int lane = threadIdx.x;  // 64
    const float* pmr = pm + (size_t)row * NBLK;
    const float* psr = ps + (size_t)row * NBLK;
    float m = -3.0e38f;
    for (int j = lane; j < NBLK; j += 64) m = fmaxf(m, pmr[j]);
#pragma unroll
    for (int d = 1; d < 64; d <<= 1) m = fmaxf(m, __shfl_xor(m, d, 64));
    float s = 0.f;
    for (int j = lane; j < NBLK; j += 64) s += psr[j] * __expf(pmr[j] - m);
#pragma unroll
    for (int d = 1; d < 64; d <<= 1) s += __shfl_xor(s, d, 64);
    if (lane == 0) ll[row] = labv[row] - m - logf(s);
}

__global__ void k_final(const float* __restrict__ ll, float* __restrict__ out) {
    int lane = threadIdx.x;  // 64
    float s = 0.f;
    for (int i = lane; i < M_; i += 64) s += ll[i];
#pragma unroll
    for (int d = 1; d < 64; d <<= 1) s += __shfl_xor(s, d, 64);
    if (lane == 0) out[0] = -s / (float)B_;
}

extern "C" void kernel_launch(void* const* d_in, const int* in_sizes, int n_in,
                              void* d_out, int out_size, void* d_ws, size_t ws_size,
                              hipStream_t stream) {
    const int* tokens = (const int*)d_in[0];
    const int* labels = (const int*)d_in[1];
    const float* emb = (const float*)d_in[2];
    const float* W1 = (const float*)d_in[3];
    const float* b1 = (const float*)d_in[4];
    const float* W2 = (const float*)d_in[5];
    const float* b2 = (const float*)d_in[6];
    const float* sw = (const float*)d_in[7];
    const float* sb = (const float*)d_in[8];
    float* out = (float*)d_out;

    char* ws = (char*)d_ws;
    size_t off = 0;
    auto alloc = [&](size_t bytes) {
        void* p = ws + off;
        off = (off + bytes + 255) & ~(size_t)255;
        return p;
    };
    unsigned short* X   = (unsigned short*)alloc((size_t)M_ * KH * 2);
    unsigned short* H1  = (unsigned short*)alloc((size_t)M_ * KH * 2);
    unsigned short* H2  = (unsigned short*)alloc((size_t)M_ * KH * 2);
    unsigned short* W1xP = (unsigned short*)alloc((size_t)N4H * KH * 2);
    unsigned short* W1hP = (unsigned short*)alloc((size_t)N4H * KH * 2);
    unsigned short* W2xP = (unsigned short*)alloc((size_t)N4H * KH * 2);
    unsigned short* W2hP = (unsigned short*)alloc((size_t)N4H * KH * 2);
    unsigned short* SWP = (unsigned short*)alloc((size_t)VP_ * KH * 2);
    float* Z  = (float*)alloc((size_t)M_ * N4H * 4);
    float* c1 = (float*)alloc((size_t)B_ * H_ * 4);
    float* c2 = (float*)alloc((size_t)B_ * H_ * 4);
    unsigned short* h0 = (unsigned short*)alloc((size_t)B_ * H_ * 2);
    float* pm = (float*)alloc((size_t)M_ * NBLK * 4);
    float* ps = (float*)alloc((size_t)M_ * NBLK * 4);
    float* labv = (float*)alloc((size_t)M_ * 4);
    int*   lab_r = (int*)alloc((size_t)M_ * 4);
    float* ll = (float*)alloc((size_t)M_ * 4);

    // setup
    k_init<<<32, 256, 0, stream>>>(labels, lab_r, c1, c2, h0);
    k_embed<<<(M_ * H_) / 256, 256, 0, stream>>>(tokens, emb, X);
    k_pack<<<512, 256, 0, stream>>>(W1,                 N4H, N4H, 2048, W1xP);
    k_pack<<<512, 256, 0, stream>>>(W1 + (size_t)512 * N4H, N4H, N4H, 2048, W1hP);
    k_pack<<<512, 256, 0, stream>>>(W2,                 N4H, N4H, 2048, W2xP);
    k_pack<<<512, 256, 0, stream>>>(W2 + (size_t)512 * N4H, N4H, N4H, 2048, W2hP);
    k_pack<<<(VP_ * NKB + 3) / 4, 256, 0, stream>>>(sw, V_, V_, VP_ * NKB / 16, SWP);

    // layer 1
    k_gemm_bias<<<dim3(16, 16), 256, 0, stream>>>(X, W1xP, b1, Z);
    for (int t = 0; t < T_; ++t) {
        const unsigned short* hp = (t == 0) ? h0 : (H1 + (size_t)(t - 1) * B_ * H_);
        k_lstm_step<<<16, 256, 0, stream>>>(Z + (size_t)t * B_ * N4H, hp, W1hP, c1,
                                            H1 + (size_t)t * B_ * H_);
    }
    // layer 2
    k_gemm_bias<<<dim3(16, 16), 256, 0, stream>>>(H1, W2xP, b2, Z);
    for (int t = 0; t < T_; ++t) {
        const unsigned short* hp = (t == 0) ? h0 : (H2 + (size_t)(t - 1) * B_ * H_);
        k_lstm_step<<<16, 256, 0, stream>>>(Z + (size_t)t * B_ * N4H, hp, W2hP, c2,
                                            H2 + (size_t)t * B_ * H_);
    }
    // logits + loss
    k_logits<<<dim3(NBLK, 16), 256, 0, stream>>>(H2, SWP, sb, lab_r, pm, ps, labv);
    k_rowreduce<<<M_, 64, 0, stream>>>(pm, ps, labv, ll);
    k_final<<<1, 64, 0, stream>>>(ll, out);
}

// Round 2
// 1920.059 us; speedup vs baseline: 1.1980x; 1.1980x over previous
//
#include <hip/hip_runtime.h>

#define B_ 16
#define T_ 128
#define H_ 512
#define V_ 50257
#define VP_ 50304            // 393*128 (padded V)
#define NBLK 393             // VP_/128
#define M_ (B_*T_)           // 2048 rows (t*16+b)
#define N4H 2048             // 4*H
#define KH 512               // K of hidden GEMMs
#define NKB 16               // KH/32
#define NRBLK 64             // persistent recurrence grid

typedef __attribute__((ext_vector_type(8))) short short8;   // bf16x8 frag
typedef __attribute__((ext_vector_type(4))) float floatx4;

static __device__ __forceinline__ unsigned short f2bf(float f) {
    unsigned int u = __builtin_bit_cast(unsigned int, f);
    unsigned int r = (u + 0x7FFFu + ((u >> 16) & 1u)) >> 16;
    return (unsigned short)r;
}

// ---------------- init: zero h buffers + barrier, precompute per-row label ----------------
__global__ void k_init(const int* __restrict__ labels, int* __restrict__ lab_r,
                       unsigned short* __restrict__ h1buf, unsigned short* __restrict__ h2buf,
                       int* __restrict__ bar) {
    int tid = blockIdx.x * blockDim.x + threadIdx.x;
    if (tid < M_) {
        int t = tid >> 4, b = tid & 15;
        lab_r[tid] = labels[b * T_ + t];   // row order is t*16+b; labels flat is b*T+t
    }
    if (tid < 2 * B_ * H_) { h1buf[tid] = 0; h2buf[tid] = 0; }
    if (tid < 2) bar[tid] = 0;
}

// ---------------- embedding gather -> bf16 X [T*B, H] (row = t*16+b) ----------------
__global__ void k_embed(const int* __restrict__ tokens, const float* __restrict__ emb,
                        unsigned short* __restrict__ X) {
    int tid = blockIdx.x * blockDim.x + threadIdx.x;
    if (tid >= M_ * H_) return;
    int row = tid >> 9, col = tid & 511;
    int t = row >> 4, b = row & 15;
    int tok = tokens[b * T_ + t];
    X[tid] = f2bf(emb[(size_t)tok * H_ + col]);
}

// ---------------- pack fp32 weight slab into MFMA B-frag order (bf16) ----------------
// chunk = nt*nkb + kb; lane l holds B[kb*32 + (l>>4)*8 + j][nt*16 + (l&15)], j=0..7
__global__ void k_pack(const float* __restrict__ src, int ld, int nvalid, int nkb,
                       int nchunks, unsigned short* __restrict__ dst) {
    int tid = blockIdx.x * blockDim.x + threadIdx.x;
    int lane = tid & 63, chunk = tid >> 6;
    if (chunk >= nchunks) return;
    int nt = chunk / nkb, kb = chunk % nkb;
    int n = nt * 16 + (lane & 15);
    int k = kb * 32 + ((lane >> 4) << 3);
    unsigned short vals[8];
    if (n < nvalid) {
#pragma unroll
        for (int j = 0; j < 8; ++j) vals[j] = f2bf(src[(size_t)(k + j) * ld + n]);
    } else {
#pragma unroll
        for (int j = 0; j < 8; ++j) vals[j] = 0;
    }
    *(short8*)(dst + (size_t)chunk * 512 + lane * 8) = *(short8*)vals;
}

// ---------------- big GEMM + bias: Z[M, 2048] = A[M,512](bf16) @ Bp + bias ----------------
__global__ __launch_bounds__(256, 2) void k_gemm_bias(
        const unsigned short* __restrict__ A, const unsigned short* __restrict__ Bp,
        const float* __restrict__ bias, float* __restrict__ C) {
    int bn = blockIdx.x, bm = blockIdx.y;
    int tid = threadIdx.x, lane = tid & 63, w = tid >> 6;
    int wm = w >> 1, wn = w & 1;
    int l15 = lane & 15, quad = lane >> 4;
    floatx4 acc[4][4];
#pragma unroll
    for (int i = 0; i < 4; ++i)
#pragma unroll
        for (int j = 0; j < 4; ++j) acc[i][j] = (floatx4){0.f, 0.f, 0.f, 0.f};
    const unsigned short* Abase = A + (size_t)(bm * 128 + wm * 64 + l15) * KH + quad * 8;
    int ntg0 = bn * 8 + wn * 4;
#pragma unroll 4
    for (int kb = 0; kb < NKB; ++kb) {
        short8 af[4], bf[4];
#pragma unroll
        for (int mt = 0; mt < 4; ++mt) af[mt] = *(const short8*)(Abase + mt * 16 * KH + kb * 32);
#pragma unroll
        for (int nt = 0; nt < 4; ++nt)
            bf[nt] = *(const short8*)(Bp + ((size_t)(ntg0 + nt) * NKB + kb) * 512 + lane * 8);
#pragma unroll
        for (int mt = 0; mt < 4; ++mt)
#pragma unroll
            for (int nt = 0; nt < 4; ++nt)
                acc[mt][nt] = __builtin_amdgcn_mfma_f32_16x16x32_bf16(af[mt], bf[nt], acc[mt][nt], 0, 0, 0);
    }
#pragma unroll
    for (int nt = 0; nt < 4; ++nt) {
        int col = bn * 128 + wn * 64 + nt * 16 + l15;
        float bv = bias[col];
#pragma unroll
        for (int mt = 0; mt < 4; ++mt) {
            int row0 = bm * 128 + wm * 64 + mt * 16 + quad * 4;
#pragma unroll
            for (int r = 0; r < 4; ++r)
                C[(size_t)(row0 + r) * N4H + col] = acc[mt][nt][r] + bv;
        }
    }
}

// ---------------- persistent fused recurrence ----------------
// 64 blocks x 256 thr. Blocks 0..31: layer1 (16 units each); 32..63: layer2 (16 units each).
// Weights register-resident (B-frags). Diagonal fusion: super-step s does layer1(t=s),
// layer2(t=s-1). One grid barrier per super-step; h state double-buffered in global.
__global__ __launch_bounds__(256, 1) void k_recur(
        const float* __restrict__ Zpre1, const unsigned short* __restrict__ W1hP,
        const unsigned short* __restrict__ W2P, const float* __restrict__ b2,
        unsigned short* __restrict__ h1buf, unsigned short* __restrict__ h2buf,
        unsigned short* __restrict__ H2out, int* __restrict__ bar) {
    const int blk = blockIdx.x, tid = threadIdx.x;
    const int lane = tid & 63, w = tid >> 6;     // w = gate (0:i 1:j 2:f 3:o)
    const int l15 = lane & 15, quad = lane >> 4;
    const bool isL2 = blk >= 32;
    const int bj = isL2 ? blk - 32 : blk;
    const int u0 = bj * 16;
    const int uu = tid >> 4, bb = tid & 15;      // gate-math (unit, batch) per thread
    __shared__ float zs[4 * 16 * 17];

    // load register-resident B fragments
    short8 bfr[32];
    const int ntile = w * 32 + bj;
    if (!isL2) {
#pragma unroll
        for (int kb = 0; kb < 16; ++kb)
            bfr[kb] = *(const short8*)(W1hP + (size_t)(ntile * 16 + kb) * 512 + lane * 8);
    } else {
#pragma unroll
        for (int kb = 0; kb < 32; ++kb)
            bfr[kb] = *(const short8*)(W2P + (size_t)(ntile * 32 + kb) * 512 + lane * 8);
    }
    const float b2c = isL2 ? b2[w * 512 + u0 + l15] : 0.f;
    float creg = 0.f;                            // cell state for (uu, bb), in-register
    int* cnt = bar;
    int* gen = bar + 1;

    for (int s = 0; s <= T_; ++s) {
        if (!isL2 && s < T_) {
            // layer1 step t=s: z = Zpre1[s] + h1(s-1) @ W1h
            const unsigned short* hp = h1buf + (((s + 1) & 1) << 13);
            floatx4 a0 = (floatx4){0.f,0.f,0.f,0.f}, a1 = (floatx4){0.f,0.f,0.f,0.f};
#pragma unroll
            for (int kb = 0; kb < 8; ++kb) {
                short8 af = *(const short8*)(hp + l15 * H_ + kb * 32 + quad * 8);
                a0 = __builtin_amdgcn_mfma_f32_16x16x32_bf16(af, bfr[kb], a0, 0, 0, 0);
            }
#pragma unroll
            for (int kb = 8; kb < 16; ++kb) {
                short8 af = *(const short8*)(hp + l15 * H_ + kb * 32 + quad * 8);
                a1 = __builtin_amdgcn_mfma_f32_16x16x32_bf16(af, bfr[kb], a1, 0, 0, 0);
            }
            const int colg = w * 512 + u0 + l15;
#pragma unroll
            for (int r = 0; r < 4; ++r) {
                int b = quad * 4 + r;
                zs[(w * 16 + l15) * 17 + b] = a0[r] + a1[r] + Zpre1[(size_t)(s * 16 + b) * N4H + colg];
            }
            __syncthreads();
            float zi = zs[(0 * 16 + uu) * 17 + bb];
            float zj = zs[(1 * 16 + uu) * 17 + bb];
            float zf = zs[(2 * 16 + uu) * 17 + bb];
            float zo = zs[(3 * 16 + uu) * 17 + bb];
            float si = 1.f / (1.f + __expf(-zi));
            float sf = 1.f / (1.f + __expf(-zf));
            float so = 1.f / (1.f + __expf(-zo));
            float cn = creg * sf + si * tanhf(zj);
            creg = cn;
            float hn = tanhf(cn) * so;
            h1buf[((s & 1) << 13) + bb * H_ + u0 + uu] = f2bf(hn);
        } else if (isL2 && s >= 1) {
            // layer2 step t=s-1: z = [h1(s-1); h2(s-2)] @ W2 + b2
            const int t = s - 1;
            const unsigned short* h1p = h1buf + (((s + 1) & 1) << 13);
            const unsigned short* h2p = h2buf + ((s & 1) << 13);
            floatx4 a0 = (floatx4){0.f,0.f,0.f,0.f}, a1 = (floatx4){0.f,0.f,0.f,0.f};
#pragma unroll
            for (int kb = 0; kb < 16; ++kb) {
                short8 af = *(const short8*)(h1p + l15 * H_ + kb * 32 + quad * 8);
                a0 = __builtin_amdgcn_mfma_f32_16x16x32_bf16(af, bfr[kb], a0, 0, 0, 0);
            }
#pragma unroll
            for (int kb = 0; kb < 16; ++kb) {
                short8 af = *(const short8*)(h2p + l15 * H_ + kb * 32 + quad * 8);
                a1 = __builtin_amdgcn_mfma_f32_16x16x32_bf16(af, bfr[16 + kb], a1, 0, 0, 0);
            }
#pragma unroll
            for (int r = 0; r < 4; ++r) {
                int b = quad * 4 + r;
                zs[(w * 16 + l15) * 17 + b] = a0[r] + a1[r] + b2c;
            }
            __syncthreads();
            float zi = zs[(0 * 16 + uu) * 17 + bb];
            float zj = zs[(1 * 16 + uu) * 17 + bb];
            float zf = zs[(2 * 16 + uu) * 17 + bb];
            float zo = zs[(3 * 16 + uu) * 17 + bb];
            float si = 1.f / (1.f + __expf(-zi));
            float sf = 1.f / (1.f + __expf(-zf));
            float so = 1.f / (1.f + __expf(-zo));
            float cn = creg * sf + si * tanhf(zj);
            creg = cn;
            float hn = tanhf(cn) * so;
            unsigned short hb = f2bf(hn);
            h2buf[(((s + 1) & 1) << 13) + bb * H_ + u0 + uu] = hb;
            H2out[(size_t)(t * 16 + bb) * H_ + u0 + uu] = hb;
        }
        // grid barrier (skip after the last super-step)
        if (s < T_) {
            __syncthreads();
            if (tid == 0) {
                __threadfence();
                int a = __hip_atomic_fetch_add(cnt, 1, __ATOMIC_ACQ_REL, __HIP_MEMORY_SCOPE_AGENT);
                if (a == NRBLK - 1) {
                    __hip_atomic_store(cnt, 0, __ATOMIC_RELAXED, __HIP_MEMORY_SCOPE_AGENT);
                    __hip_atomic_store(gen, s + 1, __ATOMIC_RELEASE, __HIP_MEMORY_SCOPE_AGENT);
                } else {
                    while (__hip_atomic_load(gen, __ATOMIC_ACQUIRE, __HIP_MEMORY_SCOPE_AGENT) <= s) {
                        __builtin_amdgcn_s_sleep(1);
                    }
                }
            }
            __syncthreads();
        }
    }
}

// ---------------- logits GEMM + fused online-softmax partials ----------------
__global__ __launch_bounds__(256, 2) void k_logits(
        const unsigned short* __restrict__ A, const unsigned short* __restrict__ Bp,
        const float* __restrict__ sb, const int* __restrict__ lab_r,
        float* __restrict__ pm, float* __restrict__ ps, float* __restrict__ labv) {
    int bn = blockIdx.x, bm = blockIdx.y;
    int tid = threadIdx.x, lane = tid & 63, w = tid >> 6;
    int wm = w >> 1, wn = w & 1;
    int l15 = lane & 15, quad = lane >> 4;
    floatx4 acc[4][4];
#pragma unroll
    for (int i = 0; i < 4; ++i)
#pragma unroll
        for (int j = 0; j < 4; ++j) acc[i][j] = (floatx4){0.f, 0.f, 0.f, 0.f};
    const unsigned short* Abase = A + (size_t)(bm * 128 + wm * 64 + l15) * KH + quad * 8;
    int ntg0 = bn * 8 + wn * 4;
#pragma unroll 4
    for (int kb = 0; kb < NKB; ++kb) {
        short8 af[4], bf[4];
#pragma unroll
        for (int mt = 0; mt < 4; ++mt) af[mt] = *(const short8*)(Abase + mt * 16 * KH + kb * 32);
#pragma unroll
        for (int nt = 0; nt < 4; ++nt)
            bf[nt] = *(const short8*)(Bp + ((size_t)(ntg0 + nt) * NKB + kb) * 512 + lane * 8);
#pragma unroll
        for (int mt = 0; mt < 4; ++mt)
#pragma unroll
            for (int nt = 0; nt < 4; ++nt)
                acc[mt][nt] = __builtin_amdgcn_mfma_f32_16x16x32_bf16(af[mt], bf[nt], acc[mt][nt], 0, 0, 0);
    }
    __shared__ float lmax[2][128];
    __shared__ float lsum[2][128];
    float bv[4]; int colg[4]; bool valid[4];
#pragma unroll
    for (int nt = 0; nt < 4; ++nt) {
        colg[nt] = bn * 128 + wn * 64 + nt * 16 + l15;
        valid[nt] = colg[nt] < V_;
        bv[nt] = valid[nt] ? sb[colg[nt]] : 0.f;
    }
#pragma unroll
    for (int mt = 0; mt < 4; ++mt) {
        float rmax[4], rsum[4];
#pragma unroll
        for (int r = 0; r < 4; ++r) {
            float m = -3.0e38f;
#pragma unroll
            for (int nt = 0; nt < 4; ++nt) {
                float v = valid[nt] ? acc[mt][nt][r] + bv[nt] : -3.0e38f;
                acc[mt][nt][r] = v;
                m = fmaxf(m, v);
            }
#pragma unroll
            for (int d = 1; d < 16; d <<= 1) m = fmaxf(m, __shfl_xor(m, d, 16));
            rmax[r] = m;
            float s = 0.f;
#pragma unroll
            for (int nt = 0; nt < 4; ++nt)
                if (valid[nt]) s += __expf(acc[mt][nt][r] - m);
#pragma unroll
            for (int d = 1; d < 16; d <<= 1) s += __shfl_xor(s, d, 16);
            rsum[r] = s;
        }
#pragma unroll
        for (int r = 0; r < 4; ++r) {
            int lrow = wm * 64 + mt * 16 + quad * 4 + r;
            int rowg = bm * 128 + lrow;
            int lc = lab_r[rowg];
#pragma unroll
            for (int nt = 0; nt < 4; ++nt)
                if (valid[nt] && colg[nt] == lc) labv[rowg] = acc[mt][nt][r];
            if (l15 == 0) { lmax[wn][lrow] = rmax[r]; lsum[wn][lrow] = rsum[r]; }
        }
    }
    __syncthreads();
    if (tid < 128) {
        float m0 = lmax[0][tid], m1 = lmax[1][tid];
        float m = fmaxf(m0, m1);
        float s = 0.f;
        if (m0 > -1.0e30f) s += lsum[0][tid] * __expf(m0 - m);
        if (m1 > -1.0e30f) s += lsum[1][tid] * __expf(m1 - m);
        int rowg = bm * 128 + tid;
        pm[(size_t)rowg * NBLK + bn] = m;
        ps[(size_t)rowg * NBLK + bn] = s;
    }
}

// ---------------- per-row reduction over the 393 tiles ----------------
__global__ void k_rowreduce(const float* __restrict__ pm, const float* __restrict__ ps,
                            const float* __restrict__ labv, float* __restrict__ ll) {
    int row = blockIdx.x;
    int lane = threadIdx.x;  // 64
    const float* pmr = pm + (size_t)row * NBLK;
    const float* psr = ps + (size_t)row * NBLK;
    float m = -3.0e38f;
    for (int j = lane; j < NBLK; j += 64) m = fmaxf(m, pmr[j]);
#pragma unroll
    for (int d = 1; d < 64; d <<= 1) m = fmaxf(m, __shfl_xor(m, d, 64));
    float s = 0.f;
    for (int j = lane; j < NBLK; j += 64) s += psr[j] * __expf(pmr[j] - m);
#pragma unroll
    for (int d = 1; d < 64; d <<= 1) s += __shfl_xor(s, d, 64);
    if (lane == 0) ll[row] = labv[row] - m - logf(s);
}

__global__ void k_final(const float* __restrict__ ll, float* __restrict__ out) {
    int lane = threadIdx.x;  // 64
    float s = 0.f;
    for (int i = lane; i < M_; i += 64) s += ll[i];
#pragma unroll
    for (int d = 1; d < 64; d <<= 1) s += __shfl_xor(s, d, 64);
    if (lane == 0) out[0] = -s / (float)B_;
}

extern "C" void kernel_launch(void* const* d_in, const int* in_sizes, int n_in,
                              void* d_out, int out_size, void* d_ws, size_t ws_size,
                              hipStream_t stream) {
    const int* tokens = (const int*)d_in[0];
    const int* labels = (const int*)d_in[1];
    const float* emb = (const float*)d_in[2];
    const float* W1 = (const float*)d_in[3];
    const float* b1 = (const float*)d_in[4];
    const float* W2 = (const float*)d_in[5];
    const float* b2 = (const float*)d_in[6];
    const float* sw = (const float*)d_in[7];
    const float* sb = (const float*)d_in[8];
    float* out = (float*)d_out;

    char* ws = (char*)d_ws;
    size_t off = 0;
    auto alloc = [&](size_t bytes) {
        void* p = ws + off;
        off = (off + bytes + 255) & ~(size_t)255;
        return p;
    };
    unsigned short* X    = (unsigned short*)alloc((size_t)M_ * KH * 2);
    unsigned short* H2   = (unsigned short*)alloc((size_t)M_ * KH * 2);
    unsigned short* W1xP = (unsigned short*)alloc((size_t)N4H * KH * 2);
    unsigned short* W1hP = (unsigned short*)alloc((size_t)N4H * KH * 2);
    unsigned short* W2P  = (unsigned short*)alloc((size_t)N4H * KH * 2 * 2);  // K=1024
    unsigned short* SWP  = (unsigned short*)alloc((size_t)VP_ * KH * 2);
    float* Z     = (float*)alloc((size_t)M_ * N4H * 4);
    unsigned short* h1buf = (unsigned short*)alloc((size_t)2 * B_ * H_ * 2);
    unsigned short* h2buf = (unsigned short*)alloc((size_t)2 * B_ * H_ * 2);
    float* pm   = (float*)alloc((size_t)M_ * NBLK * 4);
    float* ps   = (float*)alloc((size_t)M_ * NBLK * 4);
    float* labv = (float*)alloc((size_t)M_ * 4);
    int*   lab_r = (int*)alloc((size_t)M_ * 4);
    float* ll   = (float*)alloc((size_t)M_ * 4);
    int*   bar  = (int*)alloc(64 * 4);

    // setup
    k_init<<<64, 256, 0, stream>>>(labels, lab_r, h1buf, h2buf, bar);
    k_embed<<<(M_ * H_) / 256, 256, 0, stream>>>(tokens, emb, X);
    k_pack<<<512, 256, 0, stream>>>(W1,                      N4H, N4H, 16, 2048, W1xP);
    k_pack<<<512, 256, 0, stream>>>(W1 + (size_t)512 * N4H,  N4H, N4H, 16, 2048, W1hP);
    k_pack<<<1024, 256, 0, stream>>>(W2,                     N4H, N4H, 32, 4096, W2P);
    k_pack<<<12576, 256, 0, stream>>>(sw, V_, V_, 16, (VP_ / 16) * 16, SWP);

    // layer1 input pre-GEMM: Zpre1 = X @ W1x + b1
    k_gemm_bias<<<dim3(16, 16), 256, 0, stream>>>(X, W1xP, b1, Z);

    // fused persistent recurrence (both layers, diagonal pipeline)
    k_recur<<<NRBLK, 256, 0, stream>>>(Z, W1hP, W2P, b2, h1buf, h2buf, H2, bar);

    // logits + loss
    k_logits<<<dim3(NBLK, 16), 256, 0, stream>>>(H2, SWP, sb, lab_r, pm, ps, labv);
    k_rowreduce<<<M_, 64, 0, stream>>>(pm, ps, labv, ll);
    k_final<<<1, 64, 0, stream>>>(ll, out);
}

// Round 3
// 1812.314 us; speedup vs baseline: 1.2692x; 1.0595x over previous
//
#include <hip/hip_runtime.h>

#define B_ 16
#define T_ 128
#define H_ 512
#define V_ 50257
#define VP_ 50304            // 393*128 (padded V)
#define NBLK 393             // VP_/128
#define M_ (B_*T_)           // 2048 rows (t*16+b)
#define N4H 2048             // 4*H
#define KH 512               // K of hidden GEMMs
#define NKB 16               // KH/32
#define FP_ 32               // flag pad (ints) = 128 B per flag line

typedef __attribute__((ext_vector_type(8))) short short8;   // bf16x8 frag
typedef __attribute__((ext_vector_type(4))) float floatx4;

static __device__ __forceinline__ unsigned short f2bf(float f) {
    unsigned int u = __builtin_bit_cast(unsigned int, f);
    unsigned int r = (u + 0x7FFFu + ((u >> 16) & 1u)) >> 16;
    return (unsigned short)r;
}

// ---------------- init: zero h(-1) page + flags, precompute per-row label ----------------
__global__ void k_init(const int* __restrict__ labels, int* __restrict__ lab_r,
                       unsigned short* __restrict__ zeroh, int* __restrict__ flags) {
    int tid = blockIdx.x * blockDim.x + threadIdx.x;
    if (tid < M_) {
        int t = tid >> 4, b = tid & 15;
        lab_r[tid] = labels[b * T_ + t];   // row order is t*16+b; labels flat is b*T+t
    }
    if (tid < B_ * H_) zeroh[tid] = 0;     // bf16 zero page for h(-1)
    if (tid < 32 * FP_) flags[tid] = 0;
}

// ---------------- embedding gather -> bf16 X [T*B, H] (row = t*16+b) ----------------
__global__ void k_embed(const int* __restrict__ tokens, const float* __restrict__ emb,
                        unsigned short* __restrict__ X) {
    int tid = blockIdx.x * blockDim.x + threadIdx.x;
    if (tid >= M_ * H_) return;
    int row = tid >> 9, col = tid & 511;
    int t = row >> 4, b = row & 15;
    int tok = tokens[b * T_ + t];
    X[tid] = f2bf(emb[(size_t)tok * H_ + col]);
}

// ---------------- pack fp32 weight slab into MFMA B-frag order (bf16) ----------------
// chunk = nt*nkb + kb; lane l holds B[kb*32 + (l>>4)*8 + j][nt*16 + (l&15)], j=0..7
__global__ void k_pack(const float* __restrict__ src, int ld, int nvalid, int nkb,
                       int nchunks, unsigned short* __restrict__ dst) {
    int tid = blockIdx.x * blockDim.x + threadIdx.x;
    int lane = tid & 63, chunk = tid >> 6;
    if (chunk >= nchunks) return;
    int nt = chunk / nkb, kb = chunk % nkb;
    int n = nt * 16 + (lane & 15);
    int k = kb * 32 + ((lane >> 4) << 3);
    unsigned short vals[8];
    if (n < nvalid) {
#pragma unroll
        for (int j = 0; j < 8; ++j) vals[j] = f2bf(src[(size_t)(k + j) * ld + n]);
    } else {
#pragma unroll
        for (int j = 0; j < 8; ++j) vals[j] = 0;
    }
    *(short8*)(dst + (size_t)chunk * 512 + lane * 8) = *(short8*)vals;
}

// ---------------- big GEMM + bias: Z[M, 2048] = A[M,512](bf16) @ Bp + bias ----------------
__global__ __launch_bounds__(256, 2) void k_gemm_bias(
        const unsigned short* __restrict__ A, const unsigned short* __restrict__ Bp,
        const float* __restrict__ bias, float* __restrict__ C) {
    int bn = blockIdx.x, bm = blockIdx.y;
    int tid = threadIdx.x, lane = tid & 63, w = tid >> 6;
    int wm = w >> 1, wn = w & 1;
    int l15 = lane & 15, quad = lane >> 4;
    floatx4 acc[4][4];
#pragma unroll
    for (int i = 0; i < 4; ++i)
#pragma unroll
        for (int j = 0; j < 4; ++j) acc[i][j] = (floatx4){0.f, 0.f, 0.f, 0.f};
    const unsigned short* Abase = A + (size_t)(bm * 128 + wm * 64 + l15) * KH + quad * 8;
    int ntg0 = bn * 8 + wn * 4;
#pragma unroll 4
    for (int kb = 0; kb < NKB; ++kb) {
        short8 af[4], bf[4];
#pragma unroll
        for (int mt = 0; mt < 4; ++mt) af[mt] = *(const short8*)(Abase + mt * 16 * KH + kb * 32);
#pragma unroll
        for (int nt = 0; nt < 4; ++nt)
            bf[nt] = *(const short8*)(Bp + ((size_t)(ntg0 + nt) * NKB + kb) * 512 + lane * 8);
#pragma unroll
        for (int mt = 0; mt < 4; ++mt)
#pragma unroll
            for (int nt = 0; nt < 4; ++nt)
                acc[mt][nt] = __builtin_amdgcn_mfma_f32_16x16x32_bf16(af[mt], bf[nt], acc[mt][nt], 0, 0, 0);
    }
#pragma unroll
    for (int nt = 0; nt < 4; ++nt) {
        int col = bn * 128 + wn * 64 + nt * 16 + l15;
        float bv = bias[col];
#pragma unroll
        for (int mt = 0; mt < 4; ++mt) {
            int row0 = bm * 128 + wm * 64 + mt * 16 + quad * 4;
#pragma unroll
            for (int r = 0; r < 4; ++r)
                C[(size_t)(row0 + r) * N4H + col] = acc[mt][nt][r] + bv;
        }
    }
}

// ---------------- persistent fused recurrence, flag-based dataflow sync ----------------
// 32 blocks x 512 thr. Blocks 0..15: layer1 (32 units each); 16..31: layer2 (32 units each).
// Block publishes flag[blk] = s+1 after writing step-s h. L1 step s waits {L1 flags >= s};
// L2 step s waits {L1 flags >= s+1, L2 flags >= s}. Layer1 free-runs ahead (H1 fully
// materialized, no WAR). Relaxed polls on padded per-block lines; one acquire fence/step.
__global__ __launch_bounds__(512) void k_recur(
        const float* __restrict__ Zpre1, const unsigned short* __restrict__ W1hP,
        const unsigned short* __restrict__ W2P, const float* __restrict__ b2,
        const unsigned short* __restrict__ zeroh,
        unsigned short* __restrict__ H1, unsigned short* __restrict__ H2,
        int* __restrict__ flags) {
    const int blk = blockIdx.x, tid = threadIdx.x;
    const int lane = tid & 63, w = tid >> 6;     // 8 waves
    const int l15 = lane & 15, quad = lane >> 4;
    const bool isL2 = blk >= 16;
    const int bj = isL2 ? blk - 16 : blk;
    const int g = w >> 1, half = w & 1;          // gate, col-half
    const int nt = g * 32 + bj * 2 + half;       // n-tile in packed weights
    __shared__ float zs[128 * 17];

    // register-resident B fragments (L1: K=512 -> 16 frags; L2: K=1024 -> 32 frags)
    short8 bfr[32];
    if (!isL2) {
#pragma unroll
        for (int kb = 0; kb < 16; ++kb)
            bfr[kb] = *(const short8*)(W1hP + (size_t)(nt * 16 + kb) * 512 + lane * 8);
    } else {
#pragma unroll
        for (int kb = 0; kb < 32; ++kb)
            bfr[kb] = *(const short8*)(W2P + (size_t)(nt * 32 + kb) * 512 + lane * 8);
    }
    const float b2c = isL2 ? b2[g * 512 + bj * 32 + half * 16 + l15] : 0.f;
    float creg = 0.f;                            // cell state for this thread's (u, b)

    for (int s = 0; s < T_; ++s) {
        // ---- wait for producers (wave 0 polls, relaxed; per-lane flag lines) ----
        if (w == 0 && (s > 0 || isL2)) {
            int tgt = 0x80000000;                // inactive lanes trivially pass
            int* fp = flags;
            if (!isL2) {
                if (lane < 16) { fp = flags + lane * FP_; tgt = s; }
            } else {
                if (lane < 16) { fp = flags + lane * FP_; tgt = s + 1; }       // L1 flags
                else if (lane < 32) { fp = flags + lane * FP_; tgt = s; }      // L2 flags
            }
            bool act = (!isL2 && lane < 16) || (isL2 && lane < 32);
            while (true) {
                int v = act ? __hip_atomic_load(fp, __ATOMIC_RELAXED, __HIP_MEMORY_SCOPE_AGENT)
                            : 0x7fffffff;
                if (__all(v >= tgt)) break;
                __builtin_amdgcn_s_sleep(2);
            }
        }
        __syncthreads();
        __builtin_amdgcn_fence(__ATOMIC_ACQUIRE, "agent");   // one inv/step, then plain loads

        // ---- hidden GEMM into zs ----
        if (!isL2) {
            const unsigned short* hp = (s == 0) ? zeroh : H1 + (size_t)(s - 1) * B_ * H_;
            floatx4 a0 = (floatx4){0.f,0.f,0.f,0.f}, a1 = (floatx4){0.f,0.f,0.f,0.f};
#pragma unroll
            for (int kb = 0; kb < 8; ++kb) {
                short8 af = *(const short8*)(hp + l15 * H_ + kb * 32 + quad * 8);
                a0 = __builtin_amdgcn_mfma_f32_16x16x32_bf16(af, bfr[kb], a0, 0, 0, 0);
            }
#pragma unroll
            for (int kb = 8; kb < 16; ++kb) {
                short8 af = *(const short8*)(hp + l15 * H_ + kb * 32 + quad * 8);
                a1 = __builtin_amdgcn_mfma_f32_16x16x32_bf16(af, bfr[kb], a1, 0, 0, 0);
            }
            const int colg = g * 512 + bj * 32 + half * 16 + l15;
            const int zcol = g * 32 + half * 16 + l15;
#pragma unroll
            for (int r = 0; r < 4; ++r) {
                int b = quad * 4 + r;
                zs[zcol * 17 + b] = a0[r] + a1[r] + Zpre1[(size_t)(s * 16 + b) * N4H + colg];
            }
        } else {
            const unsigned short* h1p = H1 + (size_t)s * B_ * H_;
            const unsigned short* h2p = (s == 0) ? zeroh : H2 + (size_t)(s - 1) * B_ * H_;
            floatx4 a0 = (floatx4){0.f,0.f,0.f,0.f}, a1 = (floatx4){0.f,0.f,0.f,0.f};
#pragma unroll
            for (int kb = 0; kb < 16; ++kb) {
                short8 af = *(const short8*)(h1p + l15 * H_ + kb * 32 + quad * 8);
                a0 = __builtin_amdgcn_mfma_f32_16x16x32_bf16(af, bfr[kb], a0, 0, 0, 0);
            }
#pragma unroll
            for (int kb = 0; kb < 16; ++kb) {
                short8 af = *(const short8*)(h2p + l15 * H_ + kb * 32 + quad * 8);
                a1 = __builtin_amdgcn_mfma_f32_16x16x32_bf16(af, bfr[16 + kb], a1, 0, 0, 0);
            }
            const int zcol = g * 32 + half * 16 + l15;
#pragma unroll
            for (int r = 0; r < 4; ++r)
                zs[zcol * 17 + quad * 4 + r] = a0[r] + a1[r] + b2c;
        }
        __syncthreads();

        // ---- gate math: thread -> (u, b); c in register ----
        {
            int u = tid >> 4, b = tid & 15;
            float zi = zs[(0 * 32 + u) * 17 + b];
            float zj = zs[(1 * 32 + u) * 17 + b];
            float zf = zs[(2 * 32 + u) * 17 + b];
            float zo = zs[(3 * 32 + u) * 17 + b];
            float si = 1.f / (1.f + __expf(-zi));
            float sf = 1.f / (1.f + __expf(-zf));
            float so = 1.f / (1.f + __expf(-zo));
            float cn = creg * sf + si * tanhf(zj);
            creg = cn;
            unsigned short hb = f2bf(tanhf(cn) * so);
            unsigned short* Hd = isL2 ? H2 : H1;
            Hd[(size_t)(s * 16 + b) * H_ + bj * 32 + u] = hb;
        }
        __syncthreads();
        if (tid == 0)
            __hip_atomic_store(flags + blk * FP_, s + 1, __ATOMIC_RELEASE,
                               __HIP_MEMORY_SCOPE_AGENT);
    }
}

// ---------------- logits GEMM + fused online-softmax partials ----------------
__global__ __launch_bounds__(256, 2) void k_logits(
        const unsigned short* __restrict__ A, const unsigned short* __restrict__ Bp,
        const float* __restrict__ sb, const int* __restrict__ lab_r,
        float* __restrict__ pm, float* __restrict__ ps, float* __restrict__ labv) {
    int bn = blockIdx.x, bm = blockIdx.y;
    int tid = threadIdx.x, lane = tid & 63, w = tid >> 6;
    int wm = w >> 1, wn = w & 1;
    int l15 = lane & 15, quad = lane >> 4;
    floatx4 acc[4][4];
#pragma unroll
    for (int i = 0; i < 4; ++i)
#pragma unroll
        for (int j = 0; j < 4; ++j) acc[i][j] = (floatx4){0.f, 0.f, 0.f, 0.f};
    const unsigned short* Abase = A + (size_t)(bm * 128 + wm * 64 + l15) * KH + quad * 8;
    int ntg0 = bn * 8 + wn * 4;
#pragma unroll 4
    for (int kb = 0; kb < NKB; ++kb) {
        short8 af[4], bf[4];
#pragma unroll
        for (int mt = 0; mt < 4; ++mt) af[mt] = *(const short8*)(Abase + mt * 16 * KH + kb * 32);
#pragma unroll
        for (int nt = 0; nt < 4; ++nt)
            bf[nt] = *(const short8*)(Bp + ((size_t)(ntg0 + nt) * NKB + kb) * 512 + lane * 8);
#pragma unroll
        for (int mt = 0; mt < 4; ++mt)
#pragma unroll
            for (int nt = 0; nt < 4; ++nt)
                acc[mt][nt] = __builtin_amdgcn_mfma_f32_16x16x32_bf16(af[mt], bf[nt], acc[mt][nt], 0, 0, 0);
    }
    __shared__ float lmax[2][128];
    __shared__ float lsum[2][128];
    float bv[4]; int colg[4]; bool valid[4];
#pragma unroll
    for (int nt = 0; nt < 4; ++nt) {
        colg[nt] = bn * 128 + wn * 64 + nt * 16 + l15;
        valid[nt] = colg[nt] < V_;
        bv[nt] = valid[nt] ? sb[colg[nt]] : 0.f;
    }
#pragma unroll
    for (int mt = 0; mt < 4; ++mt) {
        float rmax[4], rsum[4];
#pragma unroll
        for (int r = 0; r < 4; ++r) {
            float m = -3.0e38f;
#pragma unroll
            for (int nt = 0; nt < 4; ++nt) {
                float v = valid[nt] ? acc[mt][nt][r] + bv[nt] : -3.0e38f;
                acc[mt][nt][r] = v;
                m = fmaxf(m, v);
            }
#pragma unroll
            for (int d = 1; d < 16; d <<= 1) m = fmaxf(m, __shfl_xor(m, d, 16));
            rmax[r] = m;
            float s = 0.f;
#pragma unroll
            for (int nt = 0; nt < 4; ++nt)
                if (valid[nt]) s += __expf(acc[mt][nt][r] - m);
#pragma unroll
            for (int d = 1; d < 16; d <<= 1) s += __shfl_xor(s, d, 16);
            rsum[r] = s;
        }
#pragma unroll
        for (int r = 0; r < 4; ++r) {
            int lrow = wm * 64 + mt * 16 + quad * 4 + r;
            int rowg = bm * 128 + lrow;
            int lc = lab_r[rowg];
#pragma unroll
            for (int nt = 0; nt < 4; ++nt)
                if (valid[nt] && colg[nt] == lc) labv[rowg] = acc[mt][nt][r];
            if (l15 == 0) { lmax[wn][lrow] = rmax[r]; lsum[wn][lrow] = rsum[r]; }
        }
    }
    __syncthreads();
    if (tid < 128) {
        float m0 = lmax[0][tid], m1 = lmax[1][tid];
        float m = fmaxf(m0, m1);
        float s = 0.f;
        if (m0 > -1.0e30f) s += lsum[0][tid] * __expf(m0 - m);
        if (m1 > -1.0e30f) s += lsum[1][tid] * __expf(m1 - m);
        int rowg = bm * 128 + tid;
        pm[(size_t)rowg * NBLK + bn] = m;
        ps[(size_t)rowg * NBLK + bn] = s;
    }
}

// ---------------- per-row reduction over the 393 tiles ----------------
__global__ void k_rowreduce(const float* __restrict__ pm, const float* __restrict__ ps,
                            const float* __restrict__ labv, float* __restrict__ ll) {
    int row = blockIdx.x;
    int lane = threadIdx.x;  // 64
    const float* pmr = pm + (size_t)row * NBLK;
    const float* psr = ps + (size_t)row * NBLK;
    float m = -3.0e38f;
    for (int j = lane; j < NBLK; j += 64) m = fmaxf(m, pmr[j]);
#pragma unroll
    for (int d = 1; d < 64; d <<= 1) m = fmaxf(m, __shfl_xor(m, d, 64));
    float s = 0.f;
    for (int j = lane; j < NBLK; j += 64) s += psr[j] * __expf(pmr[j] - m);
#pragma unroll
    for (int d = 1; d < 64; d <<= 1) s += __shfl_xor(s, d, 64);
    if (lane == 0) ll[row] = labv[row] - m - logf(s);
}

__global__ void k_final(const float* __restrict__ ll, float* __restrict__ out) {
    int lane = threadIdx.x;  // 64
    float s = 0.f;
    for (int i = lane; i < M_; i += 64) s += ll[i];
#pragma unroll
    for (int d = 1; d < 64; d <<= 1) s += __shfl_xor(s, d, 64);
    if (lane == 0) out[0] = -s / (float)B_;
}

extern "C" void kernel_launch(void* const* d_in, const int* in_sizes, int n_in,
                              void* d_out, int out_size, void* d_ws, size_t ws_size,
                              hipStream_t stream) {
    const int* tokens = (const int*)d_in[0];
    const int* labels = (const int*)d_in[1];
    const float* emb = (const float*)d_in[2];
    const float* W1 = (const float*)d_in[3];
    const float* b1 = (const float*)d_in[4];
    const float* W2 = (const float*)d_in[5];
    const float* b2 = (const float*)d_in[6];
    const float* sw = (const float*)d_in[7];
    const float* sb = (const float*)d_in[8];
    float* out = (float*)d_out;

    char* ws = (char*)d_ws;
    size_t off = 0;
    auto alloc = [&](size_t bytes) {
        void* p = ws + off;
        off = (off + bytes + 255) & ~(size_t)255;
        return p;
    };
    unsigned short* X    = (unsigned short*)alloc((size_t)M_ * KH * 2);
    unsigned short* H1   = (unsigned short*)alloc((size_t)M_ * KH * 2);
    unsigned short* H2   = (unsigned short*)alloc((size_t)M_ * KH * 2);
    unsigned short* W1xP = (unsigned short*)alloc((size_t)N4H * KH * 2);
    unsigned short* W1hP = (unsigned short*)alloc((size_t)N4H * KH * 2);
    unsigned short* W2P  = (unsigned short*)alloc((size_t)N4H * KH * 2 * 2);  // K=1024
    unsigned short* SWP  = (unsigned short*)alloc((size_t)VP_ * KH * 2);
    float* Z     = (float*)alloc((size_t)M_ * N4H * 4);
    unsigned short* zeroh = (unsigned short*)alloc((size_t)B_ * H_ * 2);
    float* pm   = (float*)alloc((size_t)M_ * NBLK * 4);
    float* ps   = (float*)alloc((size_t)M_ * NBLK * 4);
    float* labv = (float*)alloc((size_t)M_ * 4);
    int*   lab_r = (int*)alloc((size_t)M_ * 4);
    float* ll   = (float*)alloc((size_t)M_ * 4);
    int*   flags = (int*)alloc((size_t)32 * FP_ * 4);

    // setup
    k_init<<<64, 256, 0, stream>>>(labels, lab_r, zeroh, flags);
    k_embed<<<(M_ * H_) / 256, 256, 0, stream>>>(tokens, emb, X);
    k_pack<<<512, 256, 0, stream>>>(W1,                      N4H, N4H, 16, 2048, W1xP);
    k_pack<<<512, 256, 0, stream>>>(W1 + (size_t)512 * N4H,  N4H, N4H, 16, 2048, W1hP);
    k_pack<<<1024, 256, 0, stream>>>(W2,                     N4H, N4H, 32, 4096, W2P);
    k_pack<<<12576, 256, 0, stream>>>(sw, V_, V_, 16, (VP_ / 16) * 16, SWP);

    // layer1 input pre-GEMM: Zpre1 = X @ W1x + b1
    k_gemm_bias<<<dim3(16, 16), 256, 0, stream>>>(X, W1xP, b1, Z);

    // fused persistent recurrence (flag-sync dataflow, layer1 free-runs)
    k_recur<<<32, 512, 0, stream>>>(Z, W1hP, W2P, b2, zeroh, H1, H2, flags);

    // logits + loss
    k_logits<<<dim3(NBLK, 16), 256, 0, stream>>>(H2, SWP, sb, lab_r, pm, ps, labv);
    k_rowreduce<<<M_, 64, 0, stream>>>(pm, ps, labv, ll);
    k_final<<<1, 64, 0, stream>>>(ll, out);
}